// Round 14
// baseline (774.623 us; speedup 1.0000x reference)
//
#include <hip/hip_runtime.h>
#include <stdint.h>

typedef unsigned int u32;
typedef unsigned long long u64;
typedef _Float16 f16;
typedef __attribute__((ext_vector_type(8))) _Float16 f16x8;
typedef __attribute__((ext_vector_type(4))) _Float16 f16x4;
typedef __attribute__((ext_vector_type(2))) _Float16 f16x2;
typedef __attribute__((ext_vector_type(4))) float f32x4;
typedef __attribute__((ext_vector_type(16))) float f32x16;

#define MFMA16(a, b, c) __builtin_amdgcn_mfma_f32_16x16x32_f16((a), (b), (c), 0, 0, 0)
#define MFMA32(a, b, c) __builtin_amdgcn_mfma_f32_32x32x16_f16((a), (b), (c), 0, 0, 0)
#define MARGIN 2.0f
#define WAITV(n) asm volatile("s_waitcnt vmcnt(" #n ")" ::: "memory")

__device__ __forceinline__ u32 ford(float x) { u32 u = __float_as_uint(x); return (u & 0x80000000u) ? ~u : (u | 0x80000000u); }
__device__ __forceinline__ float iford(u32 v) { u32 u = (v & 0x80000000u) ? (v & 0x7FFFFFFFu) : ~v; return __uint_as_float(u); }
__device__ __forceinline__ int xswz(int i, int n) { return (i & 7) * (n >> 3) + (i >> 3); }  // n%8==0

typedef __attribute__((address_space(1))) const unsigned char ga_t;
typedef __attribute__((address_space(3))) unsigned char la_t;
__device__ __forceinline__ void gl16(const void* g, void* l) {
  __builtin_amdgcn_global_load_lds((ga_t*)g, (la_t*)l, 16, 0, 0);
}

// Stage one 128-row x 32-col f16 k-tile (8KB) from plain row-major global into
// linear LDS, applying the inverse bank swizzle on the SOURCE address.
template <int LDK>
__device__ __forceinline__ void stg8k(const f16* gRowBase, int ktile, char* sdst, int tid) {
#pragma unroll
  for (int it = 0; it < 2; ++it) {
    const int u = (tid + (it << 8)) << 4;  // LDS byte offset in [0, 8192)
    const int r = u >> 6, s = (u >> 4) & 3;
    const char* src = (const char*)gRowBase + (size_t)r * (LDK * 2) + ((size_t)ktile << 6) +
                      (size_t)((s ^ ((r >> 1) & 3)) << 4);
    gl16(src, sdst + u);
  }
}

// ---------------------------------------------------------------------------
// NT-GEMM, plain row-major f16 operands, BK=32, 256 thr (4 waves),
// global_load_lds staging, D-deep circular LDS buffers, counted vmcnt + raw
// s_barrier. 2 blocks/CU for the hot modes.
// MODE 0 (K1): BM=BN=128; 3-pass split; 16x16x32 MFMA (f bit-identical).
// MODE 1 (Ep): 128x128. MODE 2 (gram): sum(C^2) atomic.
// MODE 3 (screen): BM=256, BN=128, waves 128x64 via 32x32x16 MFMA;
//                  sparse candidates + tail-pad.
// MODE 4 (y): 128x128, out fp32 + b_lin[m] + seq_last[n].
// ---------------------------------------------------------------------------
template <int MODE>
__global__ __launch_bounds__(256, (MODE == 0 || MODE == 3) ? 2 : 3) void gemm2(
    const f16* __restrict__ Ah, const f16* __restrict__ Al,
    const f16* __restrict__ Bh, const f16* __restrict__ Bl,
    int chrows,
    void* __restrict__ out0, void* __restrict__ out1,
    const float* __restrict__ bias, const float* __restrict__ aux,
    u64* __restrict__ slots) {
  constexpr bool K1 = (MODE == 0);
  constexpr bool SC = (MODE == 3);
  constexpr int LDK = (MODE == 2 || MODE == 4) ? 1024 : 512;
  constexpr int D = K1 ? 2 : 3;
  constexpr int KT = (MODE == 2 || MODE == 4) ? 32 : 16;
  constexpr int MT = SC ? 8 : 4;
  constexpr int BUF = K1 ? 32768 : (SC ? 24576 : 16384);
  constexpr int LDS_SZ = D * BUF + (SC ? 1024 : 0);
  __shared__ char lds[LDS_SZ];

  const int tid = threadIdx.x;
  const int lane = tid & 63, wid = tid >> 6;
  const int wm = wid >> 1, wn = wid & 1;

  int blkm, blkn, z = 0;
  {
    const int s = xswz(blockIdx.x, gridDim.x);
    if constexpr (MODE == 0) { blkn = s & 15; blkm = s >> 4; }
    else if constexpr (MODE == 1) { blkn = s & 3; blkm = s >> 2; z = blkm >> 3; }
    else if constexpr (MODE == 2) { blkn = s & 3; blkm = (s >> 2) & 3; z = s >> 4; }
    else if constexpr (MODE == 3) {
      const int bph = (chrows >> 8) << 3;  // m-bands(256) per head * 8
      z = s / bph;
      const int rem = s - z * bph;
      blkm = rem >> 3; blkn = rem & 7;
    } else { const int r2 = s % 24; blkm = r2 % 6; blkn = r2 / 6; z = s / 24; }
  }

  int* cntL = (int*)(lds + D * BUF);
  if constexpr (SC) cntL[tid] = 0;

  // operand base pointers
  const f16 *Ab, *Bb, *Alb = nullptr, *Blb = nullptr;
  if constexpr (MODE == 0) {
    Ab = Ah + (size_t)blkm * 65536;            // x0h [chrows][512]
    Alb = Al + (size_t)blkm * 65536;
    Bb = Bh + (size_t)blkn * 65536;            // winh [2048][512]
    Blb = Bl + (size_t)blkn * 65536;
  } else if constexpr (MODE == 1) {
    Ab = Ah + (size_t)blkm * 65536;            // eft [4096][512]
    Bb = Bh + (size_t)z * 262144 + (size_t)blkn * 65536;  // wout [4][512][512]
  } else if constexpr (MODE == 2) {
    Ab = Ah + (size_t)z * 524288 + (size_t)blkm * 131072;  // nT [4][512][1024]
    Bb = Bh + (size_t)z * 524288 + (size_t)blkn * 131072;
  } else if constexpr (MODE == 3) {
    Ab = Ah + ((size_t)z * chrows + (size_t)blkm * 256) * 512;  // fh head band (256 rows)
    Bb = Bh + (size_t)z * 524288 + (size_t)blkn * 65536;        // eft head cols (128)
  } else {
    Ab = Ah + (size_t)blkm * 131072;           // wlin [768][1024]
    Bb = Bh + (size_t)z * 524288 + (size_t)blkn * 131072;  // qT [32][512][1024]
  }

  f32x4 acc[MT][4];
  f32x16 acc32[4][2];
  if constexpr (SC) {
#pragma unroll
    for (int i = 0; i < 4; ++i)
#pragma unroll
      for (int j = 0; j < 2; ++j)
#pragma unroll
        for (int r = 0; r < 16; ++r) acc32[i][j][r] = 0.f;
  } else {
#pragma unroll
    for (int i = 0; i < MT; ++i)
#pragma unroll
      for (int j = 0; j < 4; ++j) acc[i][j] = f32x4{0.f, 0.f, 0.f, 0.f};
  }

  // stage one k-tile into buffer nb
  auto stage = [&](int kt, char* nb) {
    stg8k<LDK>(Ab, kt, nb, tid);
    if constexpr (SC) stg8k<LDK>(Ab + 65536, kt, nb + 8192, tid);  // rows 128-255
    if constexpr (K1) stg8k<LDK>(Alb, kt, nb + 8192, tid);
    stg8k<LDK>(Bb, kt, nb + 16384 - (SC || K1 ? 0 : 8192), tid);
    if constexpr (K1) stg8k<LDK>(Blb, kt, nb + 24576, tid);
  };

#pragma unroll
  for (int d = 0; d < D - 1; ++d) stage(d, lds + d * BUF);

#pragma unroll
  for (int kc = 0; kc < KT; ++kc) {
    if (kc + D - 1 < KT) stage(kc + D - 1, lds + ((kc + D - 1) % D) * BUF);
    const int nf = KT - 1 - kc;  // future tiles staged beyond kc
    if constexpr (SC) {
      if (nf >= 2) WAITV(12);
      else if (nf == 1) WAITV(6);
      else WAITV(0);
    } else if constexpr (K1) {
      if (nf >= 1) WAITV(8);
      else WAITV(0);
    } else {
      if (nf >= 2) WAITV(8);
      else if (nf == 1) WAITV(4);
      else WAITV(0);
    }
    __builtin_amdgcn_s_barrier();  // raw: does NOT drain vmcnt
    const char* cbuf = lds + (kc % D) * BUF;

    if constexpr (SC) {
      // 32x32x16 path: A rows rr in [0,256) contiguous (panels adjacent),
      // frag: row = lane&31, k-half = lane>>5 within each 16-k step.
      f16x8 a32[4], b32[2];
#pragma unroll
      for (int ks = 0; ks < 2; ++ks) {
        const int khalf = ks * 2 + (lane >> 5);
#pragma unroll
        for (int mt = 0; mt < 4; ++mt) {
          const int rr = wm * 128 + mt * 32 + (lane & 31);
          a32[mt] = *(const f16x8*)(cbuf + rr * 64 + ((khalf ^ ((rr >> 1) & 3)) << 4));
        }
#pragma unroll
        for (int nt = 0; nt < 2; ++nt) {
          const int rn = wn * 64 + nt * 32 + (lane & 31);
          b32[nt] = *(const f16x8*)(cbuf + 16384 + rn * 64 + ((khalf ^ ((rn >> 1) & 3)) << 4));
        }
        __builtin_amdgcn_s_setprio(1);
#pragma unroll
        for (int mt = 0; mt < 4; ++mt)
#pragma unroll
          for (int nt = 0; nt < 2; ++nt) acc32[mt][nt] = MFMA32(a32[mt], b32[nt], acc32[mt][nt]);
        __builtin_amdgcn_s_setprio(0);
      }
    } else {
      f16x8 ah[MT], al[4];
#pragma unroll
      for (int mt = 0; mt < MT; ++mt) {
        const int rr = wm * (MT * 16) + mt * 16 + (lane & 15);
        const int o = rr * 64 + (((lane >> 4) ^ ((rr >> 1) & 3)) << 4);
        ah[mt] = *(const f16x8*)(cbuf + o);
        if constexpr (K1) al[mt] = *(const f16x8*)(cbuf + 8192 + o);
      }
      __builtin_amdgcn_s_setprio(1);
#pragma unroll
      for (int nt = 0; nt < 4; ++nt) {
        const int rn = wn * 64 + nt * 16 + (lane & 15);
        const int o = rn * 64 + (((lane >> 4) ^ ((rn >> 1) & 3)) << 4);
        const f16x8 bh = *(const f16x8*)(cbuf + (K1 ? 16384 : 8192) + o);
        f16x8 bl;
        if constexpr (K1) bl = *(const f16x8*)(cbuf + 24576 + o);
#pragma unroll
        for (int mt = 0; mt < MT; ++mt) {
          if constexpr (K1) {
            acc[mt][nt] = MFMA16(al[mt], bh, acc[mt][nt]);
            acc[mt][nt] = MFMA16(ah[mt], bl, acc[mt][nt]);
          }
          acc[mt][nt] = MFMA16(ah[mt], bh, acc[mt][nt]);
        }
      }
      __builtin_amdgcn_s_setprio(0);
    }
    __builtin_amdgcn_s_barrier();  // all waves done reading buf kc%D
  }

  // ---- epilogues ----
  if constexpr (MODE == 0) {
    // C/D 16x16: col = lane&15, row = (lane>>4)*4 + reg
    f16* fh = (f16*)out0;
    f16* fl = (f16*)out1;
#pragma unroll
    for (int nt = 0; nt < 4; ++nt) {
      const int gc = blkn * 128 + wn * 64 + nt * 16 + (lane & 15);
      const float bv = bias[gc];
      const int h = gc >> 9, d = gc & 511;
#pragma unroll
      for (int mt = 0; mt < 4; ++mt)
#pragma unroll
        for (int r = 0; r < 4; ++r) {
          const int grow = blkm * 128 + wm * 64 + mt * 16 + ((lane >> 4) << 2) + r;
          const float v = acc[mt][nt][r] * 6.103515625e-05f + bv;  // /16384 exact
          const f16 hv = (f16)v;
          const size_t off = ((size_t)h * chrows + grow) * 512 + d;
          fh[off] = hv;
          fl[off] = (f16)(v - (float)hv);
        }
    }
  } else if constexpr (MODE == 1) {
    f16* o = (f16*)out0;  // Ep [4096][512]
#pragma unroll
    for (int nt = 0; nt < 4; ++nt) {
      const int gc = blkn * 128 + wn * 64 + nt * 16 + (lane & 15);
#pragma unroll
      for (int mt = 0; mt < 4; ++mt)
#pragma unroll
        for (int r = 0; r < 4; ++r) {
          const size_t grow = (size_t)blkm * 128 + wm * 64 + mt * 16 + ((lane >> 4) << 2) + r;
          o[grow * 512 + gc] = (f16)acc[mt][nt][r];
        }
    }
  } else if constexpr (MODE == 2) {
    float ssum = 0.f;
#pragma unroll
    for (int mt = 0; mt < 4; ++mt)
#pragma unroll
      for (int nt = 0; nt < 4; ++nt)
#pragma unroll
        for (int r = 0; r < 4; ++r) ssum += acc[mt][nt][r] * acc[mt][nt][r];
#pragma unroll
    for (int o = 1; o < 64; o <<= 1) ssum += __shfl_xor(ssum, o);
    float* wp = (float*)lds;
    __syncthreads();
    if (lane == 0) wp[wid] = ssum;
    __syncthreads();
    if (tid == 0) {
      const float p = wp[0] + wp[1] + wp[2] + wp[3];
      atomicAdd(slots + (blockIdx.x & 63), (u64)llrintf(p * 16777216.f));
    }
  } else if constexpr (MODE == 3) {
    // C/D 32x32: col = lane&31, row = (reg&3) + 8*(reg>>2) + 4*(lane>>5)
    u64* candG = (u64*)out0;
    const int h = z;
    float escol[2];
    int cc[2];
#pragma unroll
    for (int nt = 0; nt < 2; ++nt) {
      cc[nt] = blkn * 128 + wn * 64 + nt * 32 + (lane & 31);  // code idx in head
      escol[nt] = aux[h * 1024 + cc[nt]];
    }
#pragma unroll
    for (int mt = 0; mt < 4; ++mt)
#pragma unroll
      for (int r = 0; r < 16; ++r) {
        const int row_l = wm * 128 + mt * 32 + (r & 3) + 8 * (r >> 2) + 4 * (lane >> 5);
        float vals[2];
        float mn = 3.4e38f;
#pragma unroll
        for (int nt = 0; nt < 2; ++nt) {
          const float v = escol[nt] - 2.0f * acc32[mt][nt][r];
          vals[nt] = v;
          mn = fminf(mn, v);
        }
#pragma unroll
        for (int o = 1; o < 32; o <<= 1) mn = fminf(mn, __shfl_xor(mn, o));  // 32-lane half
        const float lim = mn + MARGIN;
#pragma unroll
        for (int nt = 0; nt < 2; ++nt)
          if (vals[nt] <= lim) {
            const int p = atomicAdd(&cntL[row_l], 1);
            if (p < 8) {
              const size_t grow = (size_t)blkm * 256 + row_l;
              candG[(((size_t)h * chrows + grow) * 8 + blkn) * 8 + p] =
                  ((u64)ford(vals[nt]) << 32) | (u32)cc[nt];
            }
          }
      }
    __syncthreads();  // all sparse writes issued; counters final
    {
      // tail-pad: fill this block's unwritten slots with ~0ull (memset-free)
      const int c = min(cntL[tid], 8);
      u64* dst = candG + (((size_t)h * chrows + (size_t)blkm * 256 + tid) * 8 + blkn) * 8;
      for (int j = c; j < 8; ++j) dst[j] = ~0ull;
    }
  } else {  // MODE 4
    float* oy = (float*)out0 + (size_t)z * 368640;
    const float* xseq = aux + (size_t)z * 524288 + 523776;
    float sl[4];
    int gd[4];
#pragma unroll
    for (int nt = 0; nt < 4; ++nt) {
      gd[nt] = blkn * 128 + wn * 64 + nt * 16 + (lane & 15);
      sl[nt] = xseq[gd[nt]];
    }
#pragma unroll
    for (int mt = 0; mt < 4; ++mt)
#pragma unroll
      for (int r = 0; r < 4; ++r) {
        const int p = blkm * 128 + wm * 64 + mt * 16 + ((lane >> 4) << 2) + r;
        if (p < 720) {
          const float bp = bias[p];
#pragma unroll
          for (int nt = 0; nt < 4; ++nt) oy[(size_t)p * 512 + gd[nt]] = acc[mt][nt][r] + bp + sl[nt];
        }
      }
  }
}

// ---------------------------------------------------------------------------
// Rescore: exact fp64 distances (f = fh+fl vs fp32 embed) over margin set.
// ---------------------------------------------------------------------------
__global__ __launch_bounds__(256, 4) void rescore_k(
    const u64* __restrict__ candG, const f16* __restrict__ fh,
    const f16* __restrict__ fl, const float* __restrict__ embed,
    int n0, int shCH,
    int* __restrict__ indw, float* __restrict__ indout, u64* __restrict__ cslots) {
  const int tid = threadIdx.x, lane = tid & 63, wid = tid >> 6;
  const int r = blockIdx.x * 4 + wid;  // r = h*CH + row
  const int h = r >> shCH, row = r & ((1 << shCH) - 1);
  u64 cu = candG[(size_t)r * 64 + lane];
  u64 mn = cu;
#pragma unroll
  for (int o = 1; o < 64; o <<= 1) { const u64 t = __shfl_xor(mn, o); if (t < mn) mn = t; }
  const float lim = iford((u32)(mn >> 32)) + MARGIN;
  const bool pass = iford((u32)(cu >> 32)) <= lim;  // empty slots -> NaN -> false
  u64 mask = __ballot(pass);
  float fv[8];
  {
    const size_t fo = (size_t)r * 512 + lane * 8;
    const f16x8 hv = *(const f16x8*)(fh + fo);
    const f16x8 lv = *(const f16x8*)(fl + fo);
#pragma unroll
    for (int j = 0; j < 8; ++j) fv[j] = (float)hv[j] + (float)lv[j];
  }
  double bestd = 1e300;
  int bestc = 0x7FFFFFFF;
  while (mask) {
    const int src = __ffsll((unsigned long long)mask) - 1;
    mask &= mask - 1;
    const int c = (int)(u32)__shfl(cu, src);
    const float* e = embed + ((size_t)h * 1024 + c) * 512 + lane * 8;
    const float4 e0 = *(const float4*)e, e1 = *(const float4*)(e + 4);
    const float ev[8] = {e0.x, e0.y, e0.z, e0.w, e1.x, e1.y, e1.z, e1.w};
    double sd = 0.0;
#pragma unroll
    for (int j = 0; j < 8; ++j) { const double d = (double)fv[j] - (double)ev[j]; sd += d * d; }
#pragma unroll
    for (int o = 1; o < 64; o <<= 1) sd += __shfl_xor(sd, o);
    if (sd < bestd || (sd == bestd && c < bestc)) { bestd = sd; bestc = c; }
  }
  if (lane == 0) {
    const int n = n0 + row;
    indw[(size_t)n * 4 + h] = bestc;
    indout[(size_t)n * 4 + h] = (float)bestc;
    atomicAdd(cslots + (blockIdx.x & 255), (u64)llrint(bestd * 65536.0));
  }
}

// quantized^T gather: qT[b][d][s] = f16( b_out[d] + sum_h Ep[h*1024+ind][d] )
__global__ __launch_bounds__(256) void quantize_qT(
    const int* __restrict__ indw, const f16* __restrict__ Ep,
    const float* __restrict__ b_out, f16* __restrict__ qT) {
  const int tid = threadIdx.x;
  const int b = blockIdx.x >> 4, s0 = (blockIdx.x & 15) << 6;
  __shared__ int inds[64][4];
  inds[tid >> 2][tid & 3] = indw[(size_t)(b * 1024 + s0 + (tid >> 2)) * 4 + (tid & 3)];
  __syncthreads();
  const int d0 = tid * 2;
  const float ba0 = b_out[d0], ba1 = b_out[d0 + 1];
  u32 r0[32], r1[32];
  f16 t0 = (f16)0.f, t1 = (f16)0.f;
#pragma unroll
  for (int ss = 0; ss < 64; ++ss) {
    float a0 = ba0, a1 = ba1;
#pragma unroll
    for (int h = 0; h < 4; ++h) {
      const int c = inds[ss][h];
      const f16x2 p = *(const f16x2*)(Ep + (((size_t)h * 1024 + c) * 512 + d0));
      a0 += (float)p[0];
      a1 += (float)p[1];
    }
    const f16 q0 = (f16)a0, q1 = (f16)a1;
    if (ss & 1) {
      f16x2 w0; w0[0] = t0; w0[1] = q0; __builtin_memcpy(&r0[ss >> 1], &w0, 4);
      f16x2 w1; w1[0] = t1; w1[1] = q1; __builtin_memcpy(&r1[ss >> 1], &w1, 4);
    } else { t0 = q0; t1 = q1; }
  }
  const size_t o0 = ((size_t)b * 512 + d0) * 1024 + s0;
#pragma unroll
  for (int i = 0; i < 8; ++i) {
    uint4 v; v.x = r0[4 * i]; v.y = r0[4 * i + 1]; v.z = r0[4 * i + 2]; v.w = r0[4 * i + 3];
    *(uint4*)(qT + o0 + (size_t)i * 8) = v;
  }
  const size_t o1 = o0 + 1024;
#pragma unroll
  for (int i = 0; i < 8; ++i) {
    uint4 v; v.x = r1[4 * i]; v.y = r1[4 * i + 1]; v.z = r1[4 * i + 2]; v.w = r1[4 * i + 3];
    *(uint4*)(qT + o1 + (size_t)i * 8) = v;
  }
}

// ---- prep kernels ----
__global__ __launch_bounds__(256) void prep_x0(const float* __restrict__ x, int n0,
                                               f16* __restrict__ ht, f16* __restrict__ lt) {
  const int id = blockIdx.x * 256 + threadIdx.x;
  const int k8 = id & 63, r = id >> 6;
  const int n = n0 + r, b = n >> 10;
  const float* ap = x + (size_t)n * 512 + k8 * 8;
  const float* sp = x + (size_t)b * 524288 + 523776 + k8 * 8;
  const float4 a0 = *(const float4*)ap, a1 = *(const float4*)(ap + 4);
  const float4 s0 = *(const float4*)sp, s1 = *(const float4*)(sp + 4);
  const float v[8] = {(a0.x - s0.x) * 16.f, (a0.y - s0.y) * 16.f, (a0.z - s0.z) * 16.f,
                      (a0.w - s0.w) * 16.f, (a1.x - s1.x) * 16.f, (a1.y - s1.y) * 16.f,
                      (a1.z - s1.z) * 16.f, (a1.w - s1.w) * 16.f};
  f16x8 hv, lv;
#pragma unroll
  for (int j = 0; j < 8; ++j) { const f16 h = (f16)v[j]; hv[j] = h; lv[j] = (f16)(v[j] - (float)h); }
  const size_t off = (size_t)r * 512 + k8 * 8;
  *(f16x8*)(ht + off) = hv;
  *(f16x8*)(lt + off) = lv;
}

// merged independent preps: [0,1024)=w_in split, [1024,2048)=embed cast+norms,
// [2048,2560)=w_out cast, [2560,2944)=w_lin cast
__global__ __launch_bounds__(256) void prep_all(
    const float* __restrict__ w_in, f16* __restrict__ winh, f16* __restrict__ winl,
    const float* __restrict__ em, f16* __restrict__ ef, float* __restrict__ esq,
    float* __restrict__ invn, const float* __restrict__ w_out, f16* __restrict__ woutd,
    const float* __restrict__ w_lin, f16* __restrict__ wlind) {
  const int bx = blockIdx.x;
  const int tid = threadIdx.x;
  if (bx < 1024) {
    const size_t e = ((size_t)bx * 256 + tid) * 4;
    const float4 v = *(const float4*)(w_in + e);
    const float w[4] = {v.x * 1024.f, v.y * 1024.f, v.z * 1024.f, v.w * 1024.f};
    f16x4 hv, lv;
#pragma unroll
    for (int j = 0; j < 4; ++j) { const f16 h = (f16)w[j]; hv[j] = h; lv[j] = (f16)(w[j] - (float)h); }
    *(f16x4*)(winh + e) = hv;
    *(f16x4*)(winl + e) = lv;
  } else if (bx < 2048) {
    const int lane = tid & 63, wid = tid >> 6;
    const int row = (bx - 1024) * 4 + wid;
    const float* er = em + (size_t)row * 512 + lane * 8;
    const float4 a = *(const float4*)er, b = *(const float4*)(er + 4);
    f16x8 v;
    v[0] = (f16)a.x; v[1] = (f16)a.y; v[2] = (f16)a.z; v[3] = (f16)a.w;
    v[4] = (f16)b.x; v[5] = (f16)b.y; v[6] = (f16)b.z; v[7] = (f16)b.w;
    *(f16x8*)(ef + (size_t)row * 512 + lane * 8) = v;
    float s = a.x * a.x + a.y * a.y + a.z * a.z + a.w * a.w +
              b.x * b.x + b.y * b.y + b.z * b.z + b.w * b.w;
#pragma unroll
    for (int o = 1; o < 64; o <<= 1) s += __shfl_xor(s, o);
    if (lane == 0) { esq[row] = s; invn[row] = 1.0f / sqrtf(s); }
  } else if (bx < 2560) {
    const int id = (bx - 2048) * 256 + tid;
    const int k8 = id & 63, rg = id >> 6;
    const int d = rg & 511, h = rg >> 9;
    const float* ap = w_out + (size_t)d * 2048 + h * 512 + k8 * 8;
    const float4 a0 = *(const float4*)ap, a1 = *(const float4*)(ap + 4);
    f16x8 v;
    v[0] = (f16)a0.x; v[1] = (f16)a0.y; v[2] = (f16)a0.z; v[3] = (f16)a0.w;
    v[4] = (f16)a1.x; v[5] = (f16)a1.y; v[6] = (f16)a1.z; v[7] = (f16)a1.w;
    *(f16x8*)(woutd + (size_t)h * 262144 + (size_t)d * 512 + k8 * 8) = v;
  } else {
    const int id = (bx - 2560) * 256 + tid;
    const int k8 = id & 127, row = id >> 7;
    float4 a0 = {0.f, 0.f, 0.f, 0.f}, a1 = a0;
    if (row < 720) {
      const float* ap = w_lin + (size_t)row * 1024 + k8 * 8;
      a0 = *(const float4*)ap;
      a1 = *(const float4*)(ap + 4);
    }
    f16x8 v;
    v[0] = (f16)a0.x; v[1] = (f16)a0.y; v[2] = (f16)a0.z; v[3] = (f16)a0.w;
    v[4] = (f16)a1.x; v[5] = (f16)a1.y; v[6] = (f16)a1.z; v[7] = (f16)a1.w;
    *(f16x8*)(wlind + (size_t)row * 1024 + k8 * 8) = v;
  }
}

__global__ __launch_bounds__(256) void prep_normT(const float* __restrict__ em,
                                                  const float* __restrict__ invn,
                                                  f16* __restrict__ nT) {
  __shared__ float t[64 * 65];
  const int tid = threadIdx.x;
  const int bx = blockIdx.x;
  const int h = bx >> 7, rem = bx & 127, cb = rem >> 3, db = rem & 7;
  const int c0 = cb * 64, d0 = db * 64;
  const int j = tid & 63, i0 = tid >> 6;
#pragma unroll
  for (int p = 0; p < 16; ++p) {
    const int i = p * 4 + i0;
    t[i * 65 + j] = em[(size_t)h * 524288 + (size_t)(c0 + i) * 512 + d0 + j] * invn[h * 1024 + c0 + i];
  }
  __syncthreads();
#pragma unroll
  for (int p = 0; p < 16; ++p) {
    const int i = p * 4 + i0;
    nT[(size_t)h * 524288 + (size_t)(d0 + i) * 1024 + c0 + j] = (f16)t[j * 65 + i];
  }
}

__global__ void finalize_k(const u64* __restrict__ cs, const u64* __restrict__ gs,
                           float* __restrict__ out) {
  const int lane = threadIdx.x;
  u64 c = cs[lane] + cs[lane + 64] + cs[lane + 128] + cs[lane + 192];
  u64 g = gs[lane];
#pragma unroll
  for (int o = 1; o < 64; o <<= 1) {
    c += __shfl_xor(c, o);
    g += __shfl_xor(g, o);
  }
  if (lane == 0) {
    const double commit = (double)c / 65536.0 / 67108864.0;
    const double ortho = (double)g / 16777216.0 / 4194304.0 - (1.0 / 1024.0);
    out[11927552] = (float)(commit + 0.8 * ortho);
  }
}

__global__ void ws_fail_k(float* out) {
  if (threadIdx.x == 0) out[11927552] = -777777.0f;
}

// ---------------------------------------------------------------------------
extern "C" void kernel_launch(void* const* d_in, const int* in_sizes, int n_in,
                              void* d_out, int out_size, void* d_ws, size_t ws_size,
                              hipStream_t stream) {
  (void)in_sizes; (void)n_in; (void)out_size;
  const float* x = (const float*)d_in[0];
  const float* w_in = (const float*)d_in[1];
  const float* b_in = (const float*)d_in[2];
  const float* embed = (const float*)d_in[3];
  const float* w_out = (const float*)d_in[4];
  const float* b_out = (const float*)d_in[5];
  const float* w_lin = (const float*)d_in[6];
  const float* b_lin = (const float*)d_in[7];
  float* out = (float*)d_out;
  char* ws = (char*)d_ws;

  constexpr size_t SZ_WIN = 2097152, SZ_EFT = 4194304, SZ_WOUT = 2097152;
  constexpr size_t SZ_EP = 4194304, SZ_WLIN = 1572864, SZ_NT = 4194304;
  constexpr size_t SZ_SMALL = 16384 + 16384 + 524288 + 2048 + 512;
  constexpr size_t FIXED = SZ_WIN * 2 + SZ_EFT + SZ_WOUT + SZ_EP + SZ_WLIN + SZ_NT + SZ_SMALL;

  int CH = 16384, shCH = 14;
  if (ws_size < FIXED + (size_t)16384 * 12288) { CH = 8192; shCH = 13; }
  if (ws_size < FIXED + (size_t)CH * 12288) {
    ws_fail_k<<<1, 64, 0, stream>>>(out);
    return;
  }

  size_t off = 0;
  f16* x0h = (f16*)(ws + off); off += (size_t)CH * 1024;
  f16* x0l = (f16*)(ws + off); off += (size_t)CH * 1024;
  f16* fh = (f16*)(ws + off); off += (size_t)CH * 4096;
  f16* fl = (f16*)(ws + off); off += (size_t)CH * 4096;
  u64* cand = (u64*)(ws + off); off += (size_t)CH * 2048;
  f16* winh = (f16*)(ws + off); off += SZ_WIN;
  f16* winl = (f16*)(ws + off); off += SZ_WIN;
  f16* eft = (f16*)(ws + off); off += SZ_EFT;
  f16* wout = (f16*)(ws + off); off += SZ_WOUT;
  f16* Ep = (f16*)(ws + off); off += SZ_EP;
  f16* wlint = (f16*)(ws + off); off += SZ_WLIN;
  f16* nT = (f16*)(ws + off); off += SZ_NT;
  float* esq = (float*)(ws + off); off += 16384;
  float* invn = (float*)(ws + off); off += 16384;
  int* indw = (int*)(ws + off); off += 524288;
  u64* cslots = (u64*)(ws + off); off += 2048;
  u64* gslots = (u64*)(ws + off); off += 512;
  f16* qT = (f16*)ws;  // alias over x0/f after last rescore

  hipMemsetAsync((void*)cslots, 0, 2560, stream);

  prep_all<<<2944, 256, 0, stream>>>(w_in, winh, winl, embed, eft, esq, invn,
                                     w_out, wout, w_lin, wlint);
  prep_normT<<<512, 256, 0, stream>>>(embed, invn, nT);

  // Ep = embed @ w_out^T per head
  gemm2<1><<<128, 256, 0, stream>>>(eft, nullptr, wout, nullptr, 0,
                                    Ep, nullptr, nullptr, nullptr, nullptr);
  // ortho: ||N_h^T N_h||_F^2
  gemm2<2><<<64, 256, 0, stream>>>(nT, nullptr, nT, nullptr, 0,
                                   nullptr, nullptr, nullptr, nullptr, gslots);

  for (int c0 = 0; c0 < 32768; c0 += CH) {
    prep_x0<<<CH / 4, 256, 0, stream>>>(x, c0, x0h, x0l);
    // K1: f = ((x-seq_last)@w_in^T + b_in), split-f16 3-pass (16x16 MFMA, unchanged)
    gemm2<0><<<(CH / 128) * 16, 256, 0, stream>>>(x0h, x0l, winh, winl, CH,
                                                  fh, fl, b_in, nullptr, nullptr);
    // screen: 256x128 blocks via 32x32x16 MFMA, sparse candidates + tail-pad
    gemm2<3><<<(CH / 256) * 32, 256, 0, stream>>>(fh, nullptr, eft, nullptr, CH,
                                                  cand, nullptr, nullptr, esq, nullptr);
    // exact rescore -> indices + commit d^2
    rescore_k<<<CH, 256, 0, stream>>>(cand, fh, fl, embed, c0, shCH,
                                      indw, out + 11796480, cslots);
  }

  quantize_qT<<<512, 256, 0, stream>>>(indw, Ep, b_out, qT);
  // y = w_lin @ quantized + b_lin + seq_last
  gemm2<4><<<768, 256, 0, stream>>>(wlint, nullptr, qT, nullptr, 0,
                                    out, nullptr, b_lin, x, nullptr);
  finalize_k<<<1, 64, 0, stream>>>(cslots, gslots, out);
}

// Round 15
// 689.920 us; speedup vs baseline: 1.1228x; 1.1228x over previous
//
#include <hip/hip_runtime.h>
#include <stdint.h>

typedef unsigned int u32;
typedef unsigned long long u64;
typedef _Float16 f16;
typedef __attribute__((ext_vector_type(8))) _Float16 f16x8;
typedef __attribute__((ext_vector_type(4))) _Float16 f16x4;
typedef __attribute__((ext_vector_type(2))) _Float16 f16x2;
typedef __attribute__((ext_vector_type(4))) float f32x4;

#define MFMA16(a, b, c) __builtin_amdgcn_mfma_f32_16x16x32_f16((a), (b), (c), 0, 0, 0)
#define MARGIN 2.0f
#define WAITV(n) asm volatile("s_waitcnt vmcnt(" #n ")" ::: "memory")

__device__ __forceinline__ u32 ford(float x) { u32 u = __float_as_uint(x); return (u & 0x80000000u) ? ~u : (u | 0x80000000u); }
__device__ __forceinline__ float iford(u32 v) { u32 u = (v & 0x80000000u) ? (v & 0x7FFFFFFFu) : ~v; return __uint_as_float(u); }
__device__ __forceinline__ int xswz(int i, int n) { return (i & 7) * (n >> 3) + (i >> 3); }  // n%8==0

typedef __attribute__((address_space(1))) const unsigned char ga_t;
typedef __attribute__((address_space(3))) unsigned char la_t;
__device__ __forceinline__ void gl16(const void* g, void* l) {
  __builtin_amdgcn_global_load_lds((ga_t*)g, (la_t*)l, 16, 0, 0);
}

// ---- 512-thread panel stage: 128 rows x 64 cols f16 (16KB), row stride 512 f16.
// LDS slot (r, s16B) holds global 16B-slot s ^ (r&7) (inverse swizzle on source).
__device__ __forceinline__ void stgp(const f16* g, int kt, char* sdst, int tid) {
#pragma unroll
  for (int it = 0; it < 2; ++it) {
    const int u = (tid + (it << 9)) << 4;  // [0, 16384)
    const int r = u >> 7, sl = (u >> 4) & 7;
    const char* src = (const char*)g + (size_t)r * 1024 + ((size_t)kt << 7) +
                      (size_t)((sl ^ (r & 7)) << 4);
    gl16(src, sdst + u);
  }
}

// swizzled LDS frag read: panel byte base pb, row rr in [0,128), ksub in {0,1}
__device__ __forceinline__ f16x8 rdf(const char* bb, int pb, int rr, int ks, int lane) {
  return *(const f16x8*)(bb + pb + rr * 128 +
                         ((((ks << 2) + (lane >> 4)) ^ (rr & 7)) << 4));
}

// ---------------------------------------------------------------------------
// 8-wave NT-GEMM: 512 thr, BK=64, dbuf 2x64KB LDS, panel-granular prefetch,
// ONE vmcnt(0)+s_barrier per K-tile, setprio around MFMA clusters.
// MFMA issue order cycles accumulators; per-acc k-order bit-identical to all
// prior passing rounds.
// ISK1=true : 128x128 tile, 3-pass split (Ahi,Alo,Bhi,Blo) -> f16 hi/lo out.
// ISK1=false: 256x256 screen tile, score=esq-2S, slot-major dense candidate dump.
// ---------------------------------------------------------------------------
template <bool ISK1>
__global__ __launch_bounds__(512, 1) void gemm8(
    const f16* __restrict__ A0, const f16* __restrict__ A1,
    const f16* __restrict__ B0, const f16* __restrict__ B1,
    int chrows, void* __restrict__ out0, void* __restrict__ out1,
    const float* __restrict__ bias, const float* __restrict__ aux) {
  __shared__ char lds[131072 + (ISK1 ? 0 : 4096)];
  const int tid = threadIdx.x;
  const int lane = tid & 63, wid = tid >> 6;
  const int wm = wid >> 2, wn = wid & 3;

  int blkm, blkn, z = 0;
  {
    const int s = xswz(blockIdx.x, gridDim.x);
    if constexpr (ISK1) { blkn = s & 15; blkm = s >> 4; }
    else {
      const int bph = (chrows >> 8) << 2;  // blocks per head
      z = s / bph;
      const int rem = s - z * bph;
      blkm = rem >> 2; blkn = rem & 3;
    }
  }

  if constexpr (!ISK1) {  // candidate counters [256 rows][4 waves-n]
    ((int*)(lds + 131072))[tid] = 0;
    ((int*)(lds + 131072))[tid + 512] = 0;
  }

  // panel global bases (row stride 512 f16)
  const f16 *p0, *p1, *p2, *p3;
  if constexpr (ISK1) {
    p0 = A0 + (size_t)blkm * 65536;  // x0h 128-row band
    p1 = A1 + (size_t)blkm * 65536;  // x0l
    p2 = B0 + (size_t)blkn * 65536;  // winh 128-col band
    p3 = B1 + (size_t)blkn * 65536;  // winl
  } else {
    p0 = A0 + ((size_t)z * chrows + (size_t)blkm * 256) * 512;  // fh rows 0-127
    p1 = p0 + 65536;                                            // rows 128-255
    p2 = B0 + (size_t)z * 524288 + (size_t)blkn * 131072;       // eft codes 0-127
    p3 = p2 + 65536;                                            // codes 128-255
  }

  constexpr int NACC = ISK1 ? 8 : 32;
  f32x4 acc[NACC];
#pragma unroll
  for (int i = 0; i < NACC; ++i) acc[i] = f32x4{0.f, 0.f, 0.f, 0.f};

  // prologue: stage K-tile 0 into buffer 0
  stgp(p0, 0, lds + 0, tid);
  stgp(p1, 0, lds + 16384, tid);
  stgp(p2, 0, lds + 32768, tid);
  stgp(p3, 0, lds + 49152, tid);

#pragma unroll
  for (int kc = 0; kc < 8; ++kc) {
    const char* bb = lds + (kc & 1) * 65536;
    char* nb = lds + ((kc + 1) & 1) * 65536;
    const bool pf = (kc + 1 < 8);
    WAITV(0);                       // K-tile kc fully landed (issued 1 iter ago)
    __builtin_amdgcn_s_barrier();   // raw barrier: new stages issue after this

    if constexpr (!ISK1) {
      // ---- screen: per-wave 128x64 (mt 0..7, nt 0..3), 4 phases x 16 MFMA ----
      f16x8 a[4][2], b[4][2];
      const int pbA = wm * 16384;
      const int pbB = 32768 + (wn >> 1) * 16384;
      const int rB = (wn & 1) * 64 + (lane & 15);
      // P0: read A mt0-3 + B nt0-1; stage panel0; MFMA mt0-3 x nt0-1
#pragma unroll
      for (int mt = 0; mt < 4; ++mt)
#pragma unroll
        for (int ks = 0; ks < 2; ++ks) a[mt][ks] = rdf(bb, pbA, mt * 16 + (lane & 15), ks, lane);
#pragma unroll
      for (int nt = 0; nt < 2; ++nt)
#pragma unroll
        for (int ks = 0; ks < 2; ++ks) b[nt][ks] = rdf(bb, pbB, rB + nt * 16, ks, lane);
      if (pf) stgp(p0, kc + 1, nb + 0, tid);
      __builtin_amdgcn_s_setprio(1);
#pragma unroll
      for (int ks = 0; ks < 2; ++ks)
#pragma unroll
        for (int mt = 0; mt < 4; ++mt)
#pragma unroll
          for (int nt = 0; nt < 2; ++nt) acc[mt * 4 + nt] = MFMA16(a[mt][ks], b[nt][ks], acc[mt * 4 + nt]);
      __builtin_amdgcn_s_setprio(0);
      // P1: read B nt2-3; stage panel1; MFMA mt0-3 x nt2-3
#pragma unroll
      for (int nt = 2; nt < 4; ++nt)
#pragma unroll
        for (int ks = 0; ks < 2; ++ks) b[nt][ks] = rdf(bb, pbB, rB + nt * 16, ks, lane);
      if (pf) stgp(p1, kc + 1, nb + 16384, tid);
      __builtin_amdgcn_s_setprio(1);
#pragma unroll
      for (int ks = 0; ks < 2; ++ks)
#pragma unroll
        for (int mt = 0; mt < 4; ++mt)
#pragma unroll
          for (int nt = 2; nt < 4; ++nt) acc[mt * 4 + nt] = MFMA16(a[mt][ks], b[nt][ks], acc[mt * 4 + nt]);
      __builtin_amdgcn_s_setprio(0);
      // P2: read A mt4-7; stage panel2; MFMA mt4-7 x nt2-3
#pragma unroll
      for (int mt = 0; mt < 4; ++mt)
#pragma unroll
        for (int ks = 0; ks < 2; ++ks) a[mt][ks] = rdf(bb, pbA, (mt + 4) * 16 + (lane & 15), ks, lane);
      if (pf) stgp(p2, kc + 1, nb + 32768, tid);
      __builtin_amdgcn_s_setprio(1);
#pragma unroll
      for (int ks = 0; ks < 2; ++ks)
#pragma unroll
        for (int mt = 0; mt < 4; ++mt)
#pragma unroll
          for (int nt = 2; nt < 4; ++nt) acc[(mt + 4) * 4 + nt] = MFMA16(a[mt][ks], b[nt][ks], acc[(mt + 4) * 4 + nt]);
      __builtin_amdgcn_s_setprio(0);
      // P3: stage panel3; MFMA mt4-7 x nt0-1
      if (pf) stgp(p3, kc + 1, nb + 49152, tid);
      __builtin_amdgcn_s_setprio(1);
#pragma unroll
      for (int ks = 0; ks < 2; ++ks)
#pragma unroll
        for (int mt = 0; mt < 4; ++mt)
#pragma unroll
          for (int nt = 0; nt < 2; ++nt) acc[(mt + 4) * 4 + nt] = MFMA16(a[mt][ks], b[nt][ks], acc[(mt + 4) * 4 + nt]);
      __builtin_amdgcn_s_setprio(0);
    } else {
      // ---- K1: per-wave 64x32, 3-pass, 2 fat phases x 24 MFMA ----
      f16x8 ah[2][2], al[2][2], bh[2][2], bl[2][2];
      const int rA = wm * 64 + (lane & 15);
      const int rB = wn * 32 + (lane & 15);
      // Phase A: read A(hi,lo) mt0-1 + B(hi,lo) nt0-1; stage p0,p1; MFMA mt0-1 x nt0-1
#pragma unroll
      for (int mt = 0; mt < 2; ++mt)
#pragma unroll
        for (int ks = 0; ks < 2; ++ks) {
          ah[mt][ks] = rdf(bb, 0, rA + mt * 16, ks, lane);
          al[mt][ks] = rdf(bb, 16384, rA + mt * 16, ks, lane);
        }
#pragma unroll
      for (int nt = 0; nt < 2; ++nt)
#pragma unroll
        for (int ks = 0; ks < 2; ++ks) {
          bh[nt][ks] = rdf(bb, 32768, rB + nt * 16, ks, lane);
          bl[nt][ks] = rdf(bb, 49152, rB + nt * 16, ks, lane);
        }
      if (pf) { stgp(p0, kc + 1, nb + 0, tid); stgp(p1, kc + 1, nb + 16384, tid); }
      __builtin_amdgcn_s_setprio(1);
#pragma unroll
      for (int ks = 0; ks < 2; ++ks) {
#pragma unroll
        for (int mt = 0; mt < 2; ++mt)
#pragma unroll
          for (int nt = 0; nt < 2; ++nt) acc[mt * 2 + nt] = MFMA16(al[mt][ks], bh[nt][ks], acc[mt * 2 + nt]);
#pragma unroll
        for (int mt = 0; mt < 2; ++mt)
#pragma unroll
          for (int nt = 0; nt < 2; ++nt) acc[mt * 2 + nt] = MFMA16(ah[mt][ks], bl[nt][ks], acc[mt * 2 + nt]);
#pragma unroll
        for (int mt = 0; mt < 2; ++mt)
#pragma unroll
          for (int nt = 0; nt < 2; ++nt) acc[mt * 2 + nt] = MFMA16(ah[mt][ks], bh[nt][ks], acc[mt * 2 + nt]);
      }
      __builtin_amdgcn_s_setprio(0);
      // Phase B: read A mt2-3; stage p2,p3; MFMA mt2-3 x nt0-1
#pragma unroll
      for (int mt = 0; mt < 2; ++mt)
#pragma unroll
        for (int ks = 0; ks < 2; ++ks) {
          ah[mt][ks] = rdf(bb, 0, rA + (mt + 2) * 16, ks, lane);
          al[mt][ks] = rdf(bb, 16384, rA + (mt + 2) * 16, ks, lane);
        }
      if (pf) { stgp(p2, kc + 1, nb + 32768, tid); stgp(p3, kc + 1, nb + 49152, tid); }
      __builtin_amdgcn_s_setprio(1);
#pragma unroll
      for (int ks = 0; ks < 2; ++ks) {
#pragma unroll
        for (int mt = 0; mt < 2; ++mt)
#pragma unroll
          for (int nt = 0; nt < 2; ++nt) acc[(mt + 2) * 2 + nt] = MFMA16(al[mt][ks], bh[nt][ks], acc[(mt + 2) * 2 + nt]);
#pragma unroll
        for (int mt = 0; mt < 2; ++mt)
#pragma unroll
          for (int nt = 0; nt < 2; ++nt) acc[(mt + 2) * 2 + nt] = MFMA16(ah[mt][ks], bl[nt][ks], acc[(mt + 2) * 2 + nt]);
#pragma unroll
        for (int mt = 0; mt < 2; ++mt)
#pragma unroll
          for (int nt = 0; nt < 2; ++nt) acc[(mt + 2) * 2 + nt] = MFMA16(ah[mt][ks], bh[nt][ks], acc[(mt + 2) * 2 + nt]);
      }
      __builtin_amdgcn_s_setprio(0);
    }
  }

  // ---- epilogues ---- C/D: col = lane&15, row = (lane>>4)*4 + reg
  if constexpr (ISK1) {
    f16* fh = (f16*)out0;
    f16* fl = (f16*)out1;
#pragma unroll
    for (int nt = 0; nt < 2; ++nt) {
      const int gc = blkn * 128 + wn * 32 + nt * 16 + (lane & 15);
      const float bv = bias[gc];
      const int h = gc >> 9, d = gc & 511;
#pragma unroll
      for (int mt = 0; mt < 4; ++mt)
#pragma unroll
        for (int r = 0; r < 4; ++r) {
          const int grow = blkm * 128 + wm * 64 + mt * 16 + ((lane >> 4) << 2) + r;
          const float v = acc[mt * 2 + nt][r] * 6.103515625e-05f + bv;  // /16384 exact
          const f16 hv = (f16)v;
          const size_t off = ((size_t)h * chrows + grow) * 512 + d;
          fh[off] = hv;
          fl[off] = (f16)(v - (float)hv);
        }
    }
  } else {
    // dense candidate collection: SLOT-MAJOR candL (conflict-free scatter + dump)
    __syncthreads();  // all waves done with dbuf reads
    u64* candL = (u64*)lds;  // candL[slot s in 0..15][row 0..255] = 32 KB
    int* cntL = (int*)(lds + 131072);
    for (int i = tid; i < 4096; i += 512) candL[i] = ~0ull;
    __syncthreads();
    u64* candG = (u64*)out0;
    const int h = z;
    float escol[4];
    int cc[4];
#pragma unroll
    for (int nt = 0; nt < 4; ++nt) {
      cc[nt] = blkn * 256 + wn * 64 + nt * 16 + (lane & 15);  // code idx in head
      escol[nt] = aux[h * 1024 + cc[nt]];
    }
#pragma unroll
    for (int mt = 0; mt < 8; ++mt)
#pragma unroll
      for (int r = 0; r < 4; ++r) {
        const int row_l = wm * 128 + mt * 16 + ((lane >> 4) << 2) + r;  // [0,256)
        float vals[4];
        float mn = 3.4e38f;
#pragma unroll
        for (int nt = 0; nt < 4; ++nt) {
          const float v = escol[nt] - 2.0f * acc[mt * 4 + nt][r];
          vals[nt] = v;
          mn = fminf(mn, v);
        }
#pragma unroll
        for (int o = 1; o < 16; o <<= 1) mn = fminf(mn, __shfl_xor(mn, o));
        const float lim = mn + MARGIN;
#pragma unroll
        for (int nt = 0; nt < 4; ++nt)
          if (vals[nt] <= lim) {
            const int p = atomicAdd(&cntL[row_l * 4 + wn], 1);
            if (p < 4) candL[(wn * 4 + p) * 256 + row_l] = ((u64)ford(vals[nt]) << 32) | (u32)cc[nt];
          }
      }
    __syncthreads();
    if (tid < 256) {  // dense 128B dump per row; lane-consecutive LDS reads
      const size_t grow = (size_t)blkm * 256 + tid;
      u64* dst = candG + ((size_t)h * chrows + grow) * 64 + blkn * 16;
      u64 v[16];
#pragma unroll
      for (int j = 0; j < 16; ++j) v[j] = candL[j * 256 + tid];
#pragma unroll
      for (int j = 0; j < 8; ++j) {
        uint2 lo, hi;
        __builtin_memcpy(&lo, &v[2 * j], 8);
        __builtin_memcpy(&hi, &v[2 * j + 1], 8);
        uint4 w; w.x = lo.x; w.y = lo.y; w.z = hi.x; w.w = hi.y;
        ((uint4*)dst)[j] = w;
      }
    }
  }
}

// ---------------------------------------------------------------------------
// small GEMM (modes 1,2,4) — 2-phase core, BK=32, 256 thr
// ---------------------------------------------------------------------------
template <int LDK>
__device__ __forceinline__ void stg8k(const f16* gRowBase, int ktile, char* sdst, int tid) {
#pragma unroll
  for (int it = 0; it < 2; ++it) {
    const int u = (tid + (it << 8)) << 4;
    const int r = u >> 6, s = (u >> 4) & 3;
    const char* src = (const char*)gRowBase + (size_t)r * (LDK * 2) + ((size_t)ktile << 6) +
                      (size_t)((s ^ ((r >> 1) & 3)) << 4);
    gl16(src, sdst + u);
  }
}

template <int MODE>
__global__ __launch_bounds__(256, 3) void gemm2(
    const f16* __restrict__ Ah, const f16* __restrict__ Bh,
    void* __restrict__ out0, const float* __restrict__ bias,
    const float* __restrict__ aux, u64* __restrict__ slots) {
  constexpr int LDK = (MODE == 2 || MODE == 4) ? 1024 : 512;
  constexpr int D = 3;
  constexpr int KT = (MODE == 2 || MODE == 4) ? 32 : 16;
  constexpr int BUF = 16384;
  __shared__ char lds[D * BUF];

  const int tid = threadIdx.x;
  const int lane = tid & 63, wid = tid >> 6;
  const int wm = wid >> 1, wn = wid & 1;

  int blkm, blkn, z = 0;
  {
    const int s = xswz(blockIdx.x, gridDim.x);
    if constexpr (MODE == 1) { blkn = s & 3; blkm = s >> 2; z = blkm >> 3; }
    else if constexpr (MODE == 2) { blkn = s & 3; blkm = (s >> 2) & 3; z = s >> 4; }
    else { const int r2 = s % 24; blkm = r2 % 6; blkn = r2 / 6; z = s / 24; }
  }

  const f16 *Ab, *Bb;
  if constexpr (MODE == 1) {
    Ab = Ah + (size_t)blkm * 65536;
    Bb = Bh + (size_t)z * 262144 + (size_t)blkn * 65536;
  } else if constexpr (MODE == 2) {
    Ab = Ah + (size_t)z * 524288 + (size_t)blkm * 131072;
    Bb = Bh + (size_t)z * 524288 + (size_t)blkn * 131072;
  } else {
    Ab = Ah + (size_t)blkm * 131072;
    Bb = Bh + (size_t)z * 524288 + (size_t)blkn * 131072;
  }

  f32x4 acc[4][4];
#pragma unroll
  for (int i = 0; i < 4; ++i)
#pragma unroll
    for (int j = 0; j < 4; ++j) acc[i][j] = f32x4{0.f, 0.f, 0.f, 0.f};

  auto stage = [&](int kt, char* nb) {
    stg8k<LDK>(Ab, kt, nb, tid);
    stg8k<LDK>(Bb, kt, nb + 8192, tid);
  };
#pragma unroll
  for (int d = 0; d < D - 1; ++d) stage(d, lds + d * BUF);

#pragma unroll
  for (int kc = 0; kc < KT; ++kc) {
    if (kc + D - 1 < KT) stage(kc + D - 1, lds + ((kc + D - 1) % D) * BUF);
    const int nf = KT - 1 - kc;
    if (nf >= 2) WAITV(8);
    else if (nf == 1) WAITV(4);
    else WAITV(0);
    __builtin_amdgcn_s_barrier();
    const char* cbuf = lds + (kc % D) * BUF;
    f16x8 ah[4];
#pragma unroll
    for (int mt = 0; mt < 4; ++mt) {
      const int rr = wm * 64 + mt * 16 + (lane & 15);
      ah[mt] = *(const f16x8*)(cbuf + rr * 64 + (((lane >> 4) ^ ((rr >> 1) & 3)) << 4));
    }
    __builtin_amdgcn_s_setprio(1);
#pragma unroll
    for (int nt = 0; nt < 4; ++nt) {
      const int rn = wn * 64 + nt * 16 + (lane & 15);
      const f16x8 bh = *(const f16x8*)(cbuf + 8192 + rn * 64 + (((lane >> 4) ^ ((rn >> 1) & 3)) << 4));
#pragma unroll
      for (int mt = 0; mt < 4; ++mt) acc[mt][nt] = MFMA16(ah[mt], bh, acc[mt][nt]);
    }
    __builtin_amdgcn_s_setprio(0);
    __builtin_amdgcn_s_barrier();
  }

  if constexpr (MODE == 1) {
    f16* o = (f16*)out0;
#pragma unroll
    for (int nt = 0; nt < 4; ++nt) {
      const int gc = blkn * 128 + wn * 64 + nt * 16 + (lane & 15);
#pragma unroll
      for (int mt = 0; mt < 4; ++mt)
#pragma unroll
        for (int r = 0; r < 4; ++r) {
          const size_t grow = (size_t)blkm * 128 + wm * 64 + mt * 16 + ((lane >> 4) << 2) + r;
          o[grow * 512 + gc] = (f16)acc[mt][nt][r];
        }
    }
  } else if constexpr (MODE == 2) {
    float ssum = 0.f;
#pragma unroll
    for (int mt = 0; mt < 4; ++mt)
#pragma unroll
      for (int nt = 0; nt < 4; ++nt)
#pragma unroll
        for (int r = 0; r < 4; ++r) ssum += acc[mt][nt][r] * acc[mt][nt][r];
#pragma unroll
    for (int o = 1; o < 64; o <<= 1) ssum += __shfl_xor(ssum, o);
    float* wp = (float*)lds;
    __syncthreads();
    if (lane == 0) wp[wid] = ssum;
    __syncthreads();
    if (tid == 0) {
      const float p = wp[0] + wp[1] + wp[2] + wp[3];
      atomicAdd(slots + (blockIdx.x & 63), (u64)llrintf(p * 16777216.f));
    }
  } else {
    float* oy = (float*)out0 + (size_t)z * 368640;
    const float* xseq = aux + (size_t)z * 524288 + 523776;
    float sl[4];
    int gd[4];
#pragma unroll
    for (int nt = 0; nt < 4; ++nt) {
      gd[nt] = blkn * 128 + wn * 64 + nt * 16 + (lane & 15);
      sl[nt] = xseq[gd[nt]];
    }
#pragma unroll
    for (int mt = 0; mt < 4; ++mt)
#pragma unroll
      for (int r = 0; r < 4; ++r) {
        const int p = blkm * 128 + wm * 64 + mt * 16 + ((lane >> 4) << 2) + r;
        if (p < 720) {
          const float bp = bias[p];
#pragma unroll
          for (int nt = 0; nt < 4; ++nt) oy[(size_t)p * 512 + gd[nt]] = acc[mt][nt][r] + bp + sl[nt];
        }
      }
  }
}

// ---------------------------------------------------------------------------
// Rescore: exact fp64 distances (f = fh+fl vs fp32 embed) over margin set.
// ---------------------------------------------------------------------------
__global__ __launch_bounds__(256, 4) void rescore_k(
    const u64* __restrict__ candG, const f16* __restrict__ fh,
    const f16* __restrict__ fl, const float* __restrict__ embed,
    int n0, int shCH,
    int* __restrict__ indw, float* __restrict__ indout, u64* __restrict__ cslots) {
  const int tid = threadIdx.x, lane = tid & 63, wid = tid >> 6;
  const int r = blockIdx.x * 4 + wid;  // r = h*CH + row
  const int h = r >> shCH, row = r & ((1 << shCH) - 1);
  u64 cu = candG[(size_t)r * 64 + lane];
  u64 mn = cu;
#pragma unroll
  for (int o = 1; o < 64; o <<= 1) { const u64 t = __shfl_xor(mn, o); if (t < mn) mn = t; }
  const float lim = iford((u32)(mn >> 32)) + MARGIN;
  const bool pass = iford((u32)(cu >> 32)) <= lim;  // empty slots -> NaN -> false
  u64 mask = __ballot(pass);
  float fv[8];
  {
    const size_t fo = (size_t)r * 512 + lane * 8;
    const f16x8 hv = *(const f16x8*)(fh + fo);
    const f16x8 lv = *(const f16x8*)(fl + fo);
#pragma unroll
    for (int j = 0; j < 8; ++j) fv[j] = (float)hv[j] + (float)lv[j];
  }
  double bestd = 1e300;
  int bestc = 0x7FFFFFFF;
  while (mask) {
    const int src = __ffsll((unsigned long long)mask) - 1;
    mask &= mask - 1;
    const int c = (int)(u32)__shfl(cu, src);
    const float* e = embed + ((size_t)h * 1024 + c) * 512 + lane * 8;
    const float4 e0 = *(const float4*)e, e1 = *(const float4*)(e + 4);
    const float ev[8] = {e0.x, e0.y, e0.z, e0.w, e1.x, e1.y, e1.z, e1.w};
    double sd = 0.0;
#pragma unroll
    for (int j = 0; j < 8; ++j) { const double d = (double)fv[j] - (double)ev[j]; sd += d * d; }
#pragma unroll
    for (int o = 1; o < 64; o <<= 1) sd += __shfl_xor(sd, o);
    if (sd < bestd || (sd == bestd && c < bestc)) { bestd = sd; bestc = c; }
  }
  if (lane == 0) {
    const int n = n0 + row;
    indw[(size_t)n * 4 + h] = bestc;
    indout[(size_t)n * 4 + h] = (float)bestc;
    atomicAdd(cslots + (blockIdx.x & 255), (u64)llrint(bestd * 65536.0));
  }
}

// quantized^T gather: qT[b][d][s] = f16( b_out[d] + sum_h Ep[h*1024+ind][d] )
__global__ __launch_bounds__(256) void quantize_qT(
    const int* __restrict__ indw, const f16* __restrict__ Ep,
    const float* __restrict__ b_out, f16* __restrict__ qT) {
  const int tid = threadIdx.x;
  const int b = blockIdx.x >> 4, s0 = (blockIdx.x & 15) << 6;
  __shared__ int inds[64][4];
  inds[tid >> 2][tid & 3] = indw[(size_t)(b * 1024 + s0 + (tid >> 2)) * 4 + (tid & 3)];
  __syncthreads();
  const int d0 = tid * 2;
  const float ba0 = b_out[d0], ba1 = b_out[d0 + 1];
  u32 r0[32], r1[32];
  f16 t0 = (f16)0.f, t1 = (f16)0.f;
#pragma unroll
  for (int ss = 0; ss < 64; ++ss) {
    float a0 = ba0, a1 = ba1;
#pragma unroll
    for (int h = 0; h < 4; ++h) {
      const int c = inds[ss][h];
      const f16x2 p = *(const f16x2*)(Ep + (((size_t)h * 1024 + c) * 512 + d0));
      a0 += (float)p[0];
      a1 += (float)p[1];
    }
    const f16 q0 = (f16)a0, q1 = (f16)a1;
    if (ss & 1) {
      f16x2 w0; w0[0] = t0; w0[1] = q0; __builtin_memcpy(&r0[ss >> 1], &w0, 4);
      f16x2 w1; w1[0] = t1; w1[1] = q1; __builtin_memcpy(&r1[ss >> 1], &w1, 4);
    } else { t0 = q0; t1 = q1; }
  }
  const size_t o0 = ((size_t)b * 512 + d0) * 1024 + s0;
#pragma unroll
  for (int i = 0; i < 8; ++i) {
    uint4 v; v.x = r0[4 * i]; v.y = r0[4 * i + 1]; v.z = r0[4 * i + 2]; v.w = r0[4 * i + 3];
    *(uint4*)(qT + o0 + (size_t)i * 8) = v;
  }
  const size_t o1 = o0 + 1024;
#pragma unroll
  for (int i = 0; i < 8; ++i) {
    uint4 v; v.x = r1[4 * i]; v.y = r1[4 * i + 1]; v.z = r1[4 * i + 2]; v.w = r1[4 * i + 3];
    *(uint4*)(qT + o1 + (size_t)i * 8) = v;
  }
}

// ---- prep kernels ----
__global__ __launch_bounds__(256) void prep_x0(const float* __restrict__ x, int n0,
                                               f16* __restrict__ ht, f16* __restrict__ lt) {
  const int id = blockIdx.x * 256 + threadIdx.x;
  const int k8 = id & 63, r = id >> 6;
  const int n = n0 + r, b = n >> 10;
  const float* ap = x + (size_t)n * 512 + k8 * 8;
  const float* sp = x + (size_t)b * 524288 + 523776 + k8 * 8;
  const float4 a0 = *(const float4*)ap, a1 = *(const float4*)(ap + 4);
  const float4 s0 = *(const float4*)sp, s1 = *(const float4*)(sp + 4);
  const float v[8] = {(a0.x - s0.x) * 16.f, (a0.y - s0.y) * 16.f, (a0.z - s0.z) * 16.f,
                      (a0.w - s0.w) * 16.f, (a1.x - s1.x) * 16.f, (a1.y - s1.y) * 16.f,
                      (a1.z - s1.z) * 16.f, (a1.w - s1.w) * 16.f};
  f16x8 hv, lv;
#pragma unroll
  for (int j = 0; j < 8; ++j) { const f16 h = (f16)v[j]; hv[j] = h; lv[j] = (f16)(v[j] - (float)h); }
  const size_t off = (size_t)r * 512 + k8 * 8;
  *(f16x8*)(ht + off) = hv;
  *(f16x8*)(lt + off) = lv;
}

// merged independent preps: [0,1024)=w_in split, [1024,2048)=embed cast+norms,
// [2048,2560)=w_out cast, [2560,2944)=w_lin cast
__global__ __launch_bounds__(256) void prep_all(
    const float* __restrict__ w_in, f16* __restrict__ winh, f16* __restrict__ winl,
    const float* __restrict__ em, f16* __restrict__ ef, float* __restrict__ esq,
    float* __restrict__ invn, const float* __restrict__ w_out, f16* __restrict__ woutd,
    const float* __restrict__ w_lin, f16* __restrict__ wlind) {
  const int bx = blockIdx.x;
  const int tid = threadIdx.x;
  if (bx < 1024) {
    const size_t e = ((size_t)bx * 256 + tid) * 4;
    const float4 v = *(const float4*)(w_in + e);
    const float w[4] = {v.x * 1024.f, v.y * 1024.f, v.z * 1024.f, v.w * 1024.f};
    f16x4 hv, lv;
#pragma unroll
    for (int j = 0; j < 4; ++j) { const f16 h = (f16)w[j]; hv[j] = h; lv[j] = (f16)(w[j] - (float)h); }
    *(f16x4*)(winh + e) = hv;
    *(f16x4*)(winl + e) = lv;
  } else if (bx < 2048) {
    const int lane = tid & 63, wid = tid >> 6;
    const int row = (bx - 1024) * 4 + wid;
    const float* er = em + (size_t)row * 512 + lane * 8;
    const float4 a = *(const float4*)er, b = *(const float4*)(er + 4);
    f16x8 v;
    v[0] = (f16)a.x; v[1] = (f16)a.y; v[2] = (f16)a.z; v[3] = (f16)a.w;
    v[4] = (f16)b.x; v[5] = (f16)b.y; v[6] = (f16)b.z; v[7] = (f16)b.w;
    *(f16x8*)(ef + (size_t)row * 512 + lane * 8) = v;
    float s = a.x * a.x + a.y * a.y + a.z * a.z + a.w * a.w +
              b.x * b.x + b.y * b.y + b.z * b.z + b.w * b.w;
#pragma unroll
    for (int o = 1; o < 64; o <<= 1) s += __shfl_xor(s, o);
    if (lane == 0) { esq[row] = s; invn[row] = 1.0f / sqrtf(s); }
  } else if (bx < 2560) {
    const int id = (bx - 2048) * 256 + tid;
    const int k8 = id & 63, rg = id >> 6;
    const int d = rg & 511, h = rg >> 9;
    const float* ap = w_out + (size_t)d * 2048 + h * 512 + k8 * 8;
    const float4 a0 = *(const float4*)ap, a1 = *(const float4*)(ap + 4);
    f16x8 v;
    v[0] = (f16)a0.x; v[1] = (f16)a0.y; v[2] = (f16)a0.z; v[3] = (f16)a0.w;
    v[4] = (f16)a1.x; v[5] = (f16)a1.y; v[6] = (f16)a1.z; v[7] = (f16)a1.w;
    *(f16x8*)(woutd + (size_t)h * 262144 + (size_t)d * 512 + k8 * 8) = v;
  } else {
    const int id = (bx - 2560) * 256 + tid;
    const int k8 = id & 127, row = id >> 7;
    float4 a0 = {0.f, 0.f, 0.f, 0.f}, a1 = a0;
    if (row < 720) {
      const float* ap = w_lin + (size_t)row * 1024 + k8 * 8;
      a0 = *(const float4*)ap;
      a1 = *(const float4*)(ap + 4);
    }
    f16x8 v;
    v[0] = (f16)a0.x; v[1] = (f16)a0.y; v[2] = (f16)a0.z; v[3] = (f16)a0.w;
    v[4] = (f16)a1.x; v[5] = (f16)a1.y; v[6] = (f16)a1.z; v[7] = (f16)a1.w;
    *(f16x8*)(wlind + (size_t)row * 1024 + k8 * 8) = v;
  }
}

__global__ __launch_bounds__(256) void prep_normT(const float* __restrict__ em,
                                                  const float* __restrict__ invn,
                                                  f16* __restrict__ nT) {
  __shared__ float t[64 * 65];
  const int tid = threadIdx.x;
  const int bx = blockIdx.x;
  const int h = bx >> 7, rem = bx & 127, cb = rem >> 3, db = rem & 7;
  const int c0 = cb * 64, d0 = db * 64;
  const int j = tid & 63, i0 = tid >> 6;
#pragma unroll
  for (int p = 0; p < 16; ++p) {
    const int i = p * 4 + i0;
    t[i * 65 + j] = em[(size_t)h * 524288 + (size_t)(c0 + i) * 512 + d0 + j] * invn[h * 1024 + c0 + i];
  }
  __syncthreads();
#pragma unroll
  for (int p = 0; p < 16; ++p) {
    const int i = p * 4 + i0;
    nT[(size_t)h * 524288 + (size_t)(d0 + i) * 1024 + c0 + j] = (f16)t[j * 65 + i];
  }
}

__global__ void finalize_k(const u64* __restrict__ cs, const u64* __restrict__ gs,
                           float* __restrict__ out) {
  const int lane = threadIdx.x;
  u64 c = cs[lane] + cs[lane + 64] + cs[lane + 128] + cs[lane + 192];
  u64 g = gs[lane];
#pragma unroll
  for (int o = 1; o < 64; o <<= 1) {
    c += __shfl_xor(c, o);
    g += __shfl_xor(g, o);
  }
  if (lane == 0) {
    const double commit = (double)c / 65536.0 / 67108864.0;
    const double ortho = (double)g / 16777216.0 / 4194304.0 - (1.0 / 1024.0);
    out[11927552] = (float)(commit + 0.8 * ortho);
  }
}

__global__ void ws_fail_k(float* out) {
  if (threadIdx.x == 0) out[11927552] = -777777.0f;
}

// ---------------------------------------------------------------------------
extern "C" void kernel_launch(void* const* d_in, const int* in_sizes, int n_in,
                              void* d_out, int out_size, void* d_ws, size_t ws_size,
                              hipStream_t stream) {
  (void)in_sizes; (void)n_in; (void)out_size;
  const float* x = (const float*)d_in[0];
  const float* w_in = (const float*)d_in[1];
  const float* b_in = (const float*)d_in[2];
  const float* embed = (const float*)d_in[3];
  const float* w_out = (const float*)d_in[4];
  const float* b_out = (const float*)d_in[5];
  const float* w_lin = (const float*)d_in[6];
  const float* b_lin = (const float*)d_in[7];
  float* out = (float*)d_out;
  char* ws = (char*)d_ws;

  constexpr size_t SZ_WIN = 2097152, SZ_EFT = 4194304, SZ_WOUT = 2097152;
  constexpr size_t SZ_EP = 4194304, SZ_WLIN = 1572864, SZ_NT = 4194304;
  constexpr size_t SZ_SMALL = 16384 + 16384 + 524288 + 2048 + 512;
  constexpr size_t FIXED = SZ_WIN * 2 + SZ_EFT + SZ_WOUT + SZ_EP + SZ_WLIN + SZ_NT + SZ_SMALL;

  int CH = 16384, shCH = 14;
  if (ws_size < FIXED + (size_t)16384 * 12288) { CH = 8192; shCH = 13; }
  if (ws_size < FIXED + (size_t)CH * 12288) {
    ws_fail_k<<<1, 64, 0, stream>>>(out);
    return;
  }

  size_t off = 0;
  f16* x0h = (f16*)(ws + off); off += (size_t)CH * 1024;
  f16* x0l = (f16*)(ws + off); off += (size_t)CH * 1024;
  f16* fh = (f16*)(ws + off); off += (size_t)CH * 4096;
  f16* fl = (f16*)(ws + off); off += (size_t)CH * 4096;
  u64* cand = (u64*)(ws + off); off += (size_t)CH * 2048;
  f16* winh = (f16*)(ws + off); off += SZ_WIN;
  f16* winl = (f16*)(ws + off); off += SZ_WIN;
  f16* eft = (f16*)(ws + off); off += SZ_EFT;
  f16* wout = (f16*)(ws + off); off += SZ_WOUT;
  f16* Ep = (f16*)(ws + off); off += SZ_EP;
  f16* wlint = (f16*)(ws + off); off += SZ_WLIN;
  f16* nT = (f16*)(ws + off); off += SZ_NT;
  float* esq = (float*)(ws + off); off += 16384;
  float* invn = (float*)(ws + off); off += 16384;
  int* indw = (int*)(ws + off); off += 524288;
  u64* cslots = (u64*)(ws + off); off += 2048;
  u64* gslots = (u64*)(ws + off); off += 512;
  f16* qT = (f16*)ws;  // alias over x0/f after last rescore

  hipMemsetAsync((void*)cslots, 0, 2560, stream);

  prep_all<<<2944, 256, 0, stream>>>(w_in, winh, winl, embed, eft, esq, invn,
                                     w_out, wout, w_lin, wlint);
  prep_normT<<<512, 256, 0, stream>>>(embed, invn, nT);

  // Ep = embed @ w_out^T per head
  gemm2<1><<<128, 256, 0, stream>>>(eft, wout, Ep, nullptr, nullptr, nullptr);
  // ortho: ||N_h^T N_h||_F^2
  gemm2<2><<<64, 256, 0, stream>>>(nT, nT, nullptr, nullptr, nullptr, gslots);

  for (int c0 = 0; c0 < 32768; c0 += CH) {
    prep_x0<<<CH / 4, 256, 0, stream>>>(x, c0, x0h, x0l);
    // K1: f = ((x-seq_last)@w_in^T + b_in), split-f16 3-pass
    gemm8<true><<<(CH / 128) * 16, 512, 0, stream>>>(x0h, x0l, winh, winl, CH,
                                                     fh, fl, b_in, nullptr);
    // screen: 256x256, slot-major dense candidate dump
    gemm8<false><<<(CH / 256) * 16, 512, 0, stream>>>(fh, nullptr, eft, nullptr, CH,
                                                      cand, nullptr, nullptr, esq);
    // exact rescore -> indices + commit d^2
    rescore_k<<<CH, 256, 0, stream>>>(cand, fh, fl, embed, c0, shCH,
                                      indw, out + 11796480, cslots);
  }

  quantize_qT<<<512, 256, 0, stream>>>(indw, Ep, b_out, qT);
  // y = w_lin @ quantized + b_lin + seq_last
  gemm2<4><<<768, 256, 0, stream>>>(wlint, qT, out, b_lin, x, nullptr);
  finalize_k<<<1, 64, 0, stream>>>(cslots, gslots, out);
}